// Round 10
// baseline (277.816 us; speedup 1.0000x reference)
//
#include <hip/hip_runtime.h>
#include <cstdint>

typedef __attribute__((ext_vector_type(8))) short bf16x8;
typedef __attribute__((ext_vector_type(4))) float f32x4;
typedef __attribute__((ext_vector_type(4))) unsigned short u16x4;
typedef unsigned short u16;

#define LOG2E 1.44269504088896340736f

__device__ __forceinline__ u16 f2bf(float f) {
  unsigned u = __builtin_bit_cast(unsigned, f);
  u += 0x7FFFu + ((u >> 16) & 1u);
  return (u16)(u >> 16);
}
__device__ __forceinline__ float bf2f(u16 h) {
  return __builtin_bit_cast(float, ((unsigned)h) << 16);
}

#define GLOAD_LDS16(g, l)                                                              \
  __builtin_amdgcn_global_load_lds((const __attribute__((address_space(1))) void*)(g), \
                                   (__attribute__((address_space(3))) void*)(l), 16, 0, 0)

// ---------------- weight transpose f32[K][N] -> bf16[N][K] ----------------
__global__ __launch_bounds__(256) void k_transpose_bf16(
    const float* __restrict__ W, u16* __restrict__ Wt, int K, int N) {
  __shared__ float tile[32][33];
  const int tid = threadIdx.x;
  const int tx = tid & 31, ty = tid >> 5;
  const int n0 = blockIdx.x * 32, k0 = blockIdx.y * 32;
#pragma unroll
  for (int i = 0; i < 32; i += 8)
    tile[ty + i][tx] = W[(size_t)(k0 + ty + i) * N + n0 + tx];
  __syncthreads();
#pragma unroll
  for (int i = 0; i < 32; i += 8)
    Wt[(size_t)(n0 + ty + i) * K + k0 + tx] = f2bf(tile[tx][ty + i]);
}

// ---------------- LayerNorm f32[row][1024] -> bf16 ----------------
__global__ __launch_bounds__(256) void k_layernorm_bf16(
    const float* __restrict__ x, const float* __restrict__ g,
    const float* __restrict__ b, u16* __restrict__ y) {
  const int row = blockIdx.x, tid = threadIdx.x;
  const float4 v = ((const float4*)(x + (size_t)row * 1024))[tid];
  float s = v.x + v.y + v.z + v.w;
#pragma unroll
  for (int m = 1; m < 64; m <<= 1) s += __shfl_xor(s, m);
  __shared__ float ps[8];
  if ((tid & 63) == 0) ps[tid >> 6] = s;
  __syncthreads();
  const float mean = (ps[0] + ps[1] + ps[2] + ps[3]) * (1.0f / 1024.0f);
  const float d0 = v.x - mean, d1 = v.y - mean, d2 = v.z - mean, d3 = v.w - mean;
  float s2 = d0 * d0 + d1 * d1 + d2 * d2 + d3 * d3;
#pragma unroll
  for (int m = 1; m < 64; m <<= 1) s2 += __shfl_xor(s2, m);
  if ((tid & 63) == 0) ps[4 + (tid >> 6)] = s2;
  __syncthreads();
  const float var = (ps[4] + ps[5] + ps[6] + ps[7]) * (1.0f / 1024.0f);
  const float rstd = rsqrtf(var + 1e-5f);
  const float4 gv = ((const float4*)g)[tid];
  const float4 bv = ((const float4*)b)[tid];
  u16x4 o;
  o[0] = f2bf(d0 * rstd * gv.x + bv.x);
  o[1] = f2bf(d1 * rstd * gv.y + bv.y);
  o[2] = f2bf(d2 * rstd * gv.z + bv.z);
  o[3] = f2bf(d3 * rstd * gv.w + bv.w);
  *(u16x4*)(y + (size_t)row * 1024 + tid * 4) = o;
}

__device__ __forceinline__ float gelu_f(float x) {
  const float u = 0.7978845608028654f * (x + 0.044715f * x * x * x);
  const float e = exp2f(u * 2.8853900817779268f);  // e^{2u}
  const float t = 1.0f - 2.0f / (e + 1.0f);        // tanh(u)
  return 0.5f * x * (1.0f + t);
}

// ---------------- 128x128 GEMM, double-buffered (the proven workhorse) ----------
// EPI 0: bf16 out
// EPI 1: f32 out + bf16 residual
// EPI 2: bf16 out + gelu
// EPI 3: qkv split: cols [0,2048) -> bf16 out row-stride 2048 (Q|K);
//        cols [2048,3072) -> vt[(bat*16+h)*64+d][2048] = V transposed per head
template <int EPI>
__global__ __launch_bounds__(256, 2) void k_gemm_bt(
    const u16* __restrict__ A, const u16* __restrict__ Bt,
    const float* __restrict__ bias, const u16* __restrict__ resid,
    void* __restrict__ out, u16* __restrict__ vt, int M, int N, int K) {
  __shared__ u16 As[2][128 * 64];
  __shared__ u16 Bs[2][128 * 64];
  const int tid = threadIdx.x;
  const int rowBase = blockIdx.y * 128, colBase = blockIdx.x * 128;
  const int w = tid >> 6, l = tid & 63;
  const int wm = w >> 1, wn = w & 1;
  const int lrow = l & 15, lg = l >> 4;
  const int srow = tid >> 3, sslot = tid & 7;

  const f32x4 fz = {0.f, 0.f, 0.f, 0.f};
  f32x4 acc[4][4];
#pragma unroll
  for (int m = 0; m < 4; m++)
#pragma unroll
    for (int n = 0; n < 4; n++) acc[m][n] = fz;

  const int NT = K >> 6;
  auto STAGE = [&](int b, int kt) {
#pragma unroll
    for (int i = 0; i < 4; i++) {
      const int r = srow + 32 * i;
      const int gs = sslot ^ (r & 7);  // inverse-swizzled source, linear LDS dest
      GLOAD_LDS16(A + (size_t)(rowBase + r) * K + kt * 64 + gs * 8,
                  (char*)As[b] + i * 4096 + tid * 16);
      GLOAD_LDS16(Bt + (size_t)(colBase + r) * K + kt * 64 + gs * 8,
                  (char*)Bs[b] + i * 4096 + tid * 16);
    }
  };

  STAGE(0, 0);
  for (int kt = 0; kt < NT; ++kt) {
    const int buf = kt & 1;
    if (kt + 1 < NT) {
      STAGE(buf ^ 1, kt + 1);  // issue next tile's loads BEFORE waiting on current
      asm volatile("s_waitcnt vmcnt(8)" ::: "memory");  // current tile done, next in flight
    } else {
      asm volatile("s_waitcnt vmcnt(0)" ::: "memory");
    }
    __builtin_amdgcn_s_barrier();
    const char* Ab = (const char*)As[buf];
    const char* Bb = (const char*)Bs[buf];
#pragma unroll
    for (int kc = 0; kc < 2; kc++) {
      bf16x8 av[4], bv[4];
#pragma unroll
      for (int m = 0; m < 4; m++) {
        const int r = wm * 64 + m * 16 + lrow;
        const int sl = (kc * 4 + lg) ^ (r & 7);
        av[m] = *(const bf16x8*)(Ab + r * 128 + sl * 16);
      }
#pragma unroll
      for (int n = 0; n < 4; n++) {
        const int r = wn * 64 + n * 16 + lrow;
        const int sl = (kc * 4 + lg) ^ (r & 7);
        bv[n] = *(const bf16x8*)(Bb + r * 128 + sl * 16);
      }
#pragma unroll
      for (int m = 0; m < 4; m++)
#pragma unroll
        for (int n = 0; n < 4; n++)
          acc[m][n] = __builtin_amdgcn_mfma_f32_16x16x32_bf16(av[m], bv[n], acc[m][n], 0, 0, 0);
    }
    __builtin_amdgcn_s_barrier();  // all waves done reading buf before next STAGE overwrites it
  }
#pragma unroll
  for (int n = 0; n < 4; n++) {
    const int col = colBase + wn * 64 + n * 16 + lrow;
    const float bval = bias[col];
#pragma unroll
    for (int m = 0; m < 4; m++) {
      const int row0 = rowBase + wm * 64 + m * 16 + lg * 4;
      if (EPI == 3 && col >= 2048) {
        const int c2 = col - 2048;
        const int hh = c2 >> 6, dd = c2 & 63;
        const int bat = row0 >> 11, tok0 = row0 & 2047;
        u16x4 pk;
#pragma unroll
        for (int r = 0; r < 4; r++) pk[r] = f2bf(acc[m][n][r] + bval);
        *(u16x4*)(vt + ((size_t)(bat * 16 + hh) * 64 + dd) * 2048 + tok0) = pk;
      } else if (EPI == 3) {
#pragma unroll
        for (int r = 0; r < 4; r++)
          ((u16*)out)[(size_t)(row0 + r) * 2048 + col] = f2bf(acc[m][n][r] + bval);
      } else {
#pragma unroll
        for (int r = 0; r < 4; r++) {
          const size_t idx = (size_t)(row0 + r) * N + col;
          float v = acc[m][n][r] + bval;
          if (EPI == 0) {
            ((u16*)out)[idx] = f2bf(v);
          } else if (EPI == 2) {
            ((u16*)out)[idx] = f2bf(gelu_f(v));
          } else {
            v += bf2f(resid[idx]);
            ((float*)out)[idx] = v;
          }
        }
      }
    }
  }
}

// ---------------- causal flash attention v4 (unchanged from R9) ----------------
__global__ __launch_bounds__(256, 4) void k_attention(
    const u16* __restrict__ qk, const u16* __restrict__ VT, u16* __restrict__ out) {
  const int S = 2048, E2 = 2048;
  const int bid = blockIdx.x;
  const int qt = 31 - (bid >> 5);
  const int bh = bid & 31;
  const int bat = bh >> 4, h = bh & 15;
  const u16* base = qk + (size_t)bat * S * E2;
  const u16* kbase = base + 1024 + h * 64;
  const u16* vbase = VT + (size_t)bh * 64 * S;  // [d][tok]
  const int tid = threadIdx.x, w = tid >> 6, l = tid & 63;
  const int lrow = l & 15, lg = l >> 4;
  __shared__ u16 Ks[2][64 * 64];
  __shared__ u16 Vs[2][64 * 64];
  __shared__ u16 Pl[4][16 * 64];
  u16* Plw = Pl[w];
  const int srow = tid >> 3, sslot = tid & 7;
  const int gs = sslot ^ (srow & 7);
  const float sc = 0.125f * LOG2E;
  const f32x4 fz = {0.f, 0.f, 0.f, 0.f};

  auto STAGE = [&](int bufi, int kb) {
#pragma unroll
    for (int round = 0; round < 2; round++) {
      const int r = srow + 32 * round;
      GLOAD_LDS16(kbase + (size_t)(kb + r) * E2 + gs * 8, (char*)Ks[bufi] + round * 4096 + tid * 16);
      GLOAD_LDS16(vbase + (size_t)r * S + kb + gs * 8, (char*)Vs[bufi] + round * 4096 + tid * 16);
    }
  };

  const int qrow0 = qt * 64 + w * 16;
  const int nkt = qt + 1;

  bf16x8 qfrag[2];
#pragma unroll
  for (int kc = 0; kc < 2; kc++)
    qfrag[kc] = *(const bf16x8*)(base + (size_t)(qrow0 + lrow) * E2 + h * 64 + kc * 32 + lg * 8);

  f32x4 o[4];
  float mrow[4], lsum[4];
#pragma unroll
  for (int r = 0; r < 4; r++) { mrow[r] = -1e30f; lsum[r] = 0.f; }
#pragma unroll
  for (int df = 0; df < 4; df++) o[df] = fz;

  STAGE(0, 0);
  __syncthreads();

  for (int kt = 0; kt < nkt; kt++) {
    const int cur = kt & 1;
    const int kb = kt * 64;
    if (kt + 1 < nkt) STAGE(cur ^ 1, kb + 64);
    const u16* Kc = Ks[cur];
    const u16* Vc = Vs[cur];

    f32x4 sv[4];
#pragma unroll
    for (int kf = 0; kf < 4; kf++) sv[kf] = fz;
#pragma unroll
    for (int kc = 0; kc < 2; kc++) {
      bf16x8 kfr[4];
#pragma unroll
      for (int kf = 0; kf < 4; kf++) {
        const int rk = kf * 16 + lrow;
        kfr[kf] = *(const bf16x8*)(Kc + rk * 64 + ((kc * 4 + lg) ^ (rk & 7)) * 8);
      }
#pragma unroll
      for (int kf = 0; kf < 4; kf++)
        sv[kf] = __builtin_amdgcn_mfma_f32_16x16x32_bf16(qfrag[kc], kfr[kf], sv[kf], 0, 0, 0);
    }
#pragma unroll
    for (int kf = 0; kf < 4; kf++)
#pragma unroll
      for (int r = 0; r < 4; r++) sv[kf][r] *= sc;
    if (kt == nkt - 1) {
#pragma unroll
      for (int kf = 0; kf < 4; kf++) {
        const int kg = kb + kf * 16 + lrow;
#pragma unroll
        for (int r = 0; r < 4; r++) {
          const int qg = qrow0 + lg * 4 + r;
          if (kg > qg) sv[kf][r] = -1e30f;
        }
      }
    }
#pragma unroll
    for (int r = 0; r < 4; r++) {
      float mx = fmaxf(fmaxf(sv[0][r], sv[1][r]), fmaxf(sv[2][r], sv[3][r]));
#pragma unroll
      for (int msk = 1; msk < 16; msk <<= 1) mx = fmaxf(mx, __shfl_xor(mx, msk));
      const float mnew = fmaxf(mrow[r], mx);
      const float corr = exp2f(mrow[r] - mnew);
      mrow[r] = mnew;
      lsum[r] *= corr;
#pragma unroll
      for (int df = 0; df < 4; df++) o[df][r] *= corr;
      float rsv = 0.f;
#pragma unroll
      for (int kf = 0; kf < 4; kf++) {
        const float p = exp2f(sv[kf][r] - mnew);
        sv[kf][r] = p;
        rsv += p;
      }
#pragma unroll
      for (int msk = 1; msk < 16; msk <<= 1) rsv += __shfl_xor(rsv, msk);
      lsum[r] += rsv;
    }
#pragma unroll
    for (int kf = 0; kf < 4; kf++)
#pragma unroll
      for (int r = 0; r < 4; r++) {
        const int q = lg * 4 + r;
        *(u16*)((char*)Plw + q * 128 + ((kf * 32 + lrow * 2) ^ ((q & 7) << 4))) = f2bf(sv[kf][r]);
      }
#pragma unroll
    for (int kc = 0; kc < 2; kc++) {
      const bf16x8 pa =
          *(const bf16x8*)((const char*)Plw + lrow * 128 + (((kc * 4 + lg) ^ (lrow & 7)) << 4));
      bf16x8 vb[4];
#pragma unroll
      for (int df = 0; df < 4; df++) {
        const int rd = df * 16 + lrow;
        vb[df] = *(const bf16x8*)(Vc + rd * 64 + ((kc * 4 + lg) ^ (rd & 7)) * 8);
      }
#pragma unroll
      for (int df = 0; df < 4; df++)
        o[df] = __builtin_amdgcn_mfma_f32_16x16x32_bf16(pa, vb[df], o[df], 0, 0, 0);
    }
    __syncthreads();
  }
#pragma unroll
  for (int r = 0; r < 4; r++) {
    const float inv = 1.0f / lsum[r];
    const int qg = qrow0 + lg * 4 + r;
#pragma unroll
    for (int df = 0; df < 4; df++) {
      const int col = h * 64 + df * 16 + lrow;
      out[(size_t)(bat * S + qg) * 1024 + col] = f2bf(o[df][r] * inv);
    }
  }
}

// ---------------- host launch ----------------
extern "C" void kernel_launch(void* const* d_in, const int* in_sizes, int n_in,
                              void* d_out, int out_size, void* d_ws, size_t ws_size,
                              hipStream_t stream) {
  (void)in_sizes; (void)n_in; (void)out_size; (void)ws_size;
  const float* x      = (const float*)d_in[0];
  const float* ln1_g  = (const float*)d_in[1];
  const float* ln1_b  = (const float*)d_in[2];
  const float* W_attn = (const float*)d_in[3];
  const float* b_attn = (const float*)d_in[4];
  const float* W_proj = (const float*)d_in[5];
  const float* b_proj = (const float*)d_in[6];
  const float* ln2_g  = (const float*)d_in[7];
  const float* ln2_b  = (const float*)d_in[8];
  const float* W_fc   = (const float*)d_in[9];
  const float* b_fc   = (const float*)d_in[10];
  const float* W_mlp  = (const float*)d_in[11];
  const float* b_mlp  = (const float*)d_in[12];

  const int M = 4096;  // B*S = 2*2048
  char* ws = (char*)d_ws;
  size_t off = 0;
  auto alloc = [&](size_t bytes) {
    void* p = ws + off;
    off += (bytes + 255) & ~(size_t)255;
    return p;
  };
  u16* WattnT = (u16*)alloc((size_t)3072 * 1024 * 2);
  u16* WprojT = (u16*)alloc((size_t)1024 * 1024 * 2);
  u16* WfcT   = (u16*)alloc((size_t)4096 * 1024 * 2);
  u16* WmlpT  = (u16*)alloc((size_t)1024 * 4096 * 2);
  u16* x1     = (u16*)alloc((size_t)M * 1024 * 2);
  u16* qkb    = (u16*)alloc((size_t)M * 2048 * 2);        // Q|K only
  u16* VT     = (u16*)alloc((size_t)32 * 64 * 2048 * 2);  // [b*h][d][tok]
  u16* attno  = (u16*)alloc((size_t)M * 1024 * 2);
  float* x2   = (float*)alloc((size_t)M * 1024 * 4);
  u16* x3     = (u16*)alloc((size_t)M * 1024 * 2);
  u16* hbuf   = (u16*)alloc((size_t)M * 4096 * 2);

  const dim3 blk(256);
  k_transpose_bf16<<<dim3(3072 / 32, 1024 / 32), blk, 0, stream>>>(W_attn, WattnT, 1024, 3072);
  k_transpose_bf16<<<dim3(1024 / 32, 1024 / 32), blk, 0, stream>>>(W_proj, WprojT, 1024, 1024);
  k_transpose_bf16<<<dim3(4096 / 32, 1024 / 32), blk, 0, stream>>>(W_fc, WfcT, 1024, 4096);
  k_transpose_bf16<<<dim3(1024 / 32, 4096 / 32), blk, 0, stream>>>(W_mlp, WmlpT, 4096, 1024);

  k_layernorm_bf16<<<M, blk, 0, stream>>>(x, ln1_g, ln1_b, x1);
  // QKV: dbuf 128^2, grid 24x32, EPI3 split epilogue (Q|K + transposed V)
  k_gemm_bt<3><<<dim3(3072 / 128, M / 128), blk, 0, stream>>>(
      x1, WattnT, b_attn, nullptr, qkb, VT, M, 3072, 1024);
  k_attention<<<dim3(1024), blk, 0, stream>>>(qkb, VT, attno);
  k_gemm_bt<1><<<dim3(1024 / 128, M / 128), blk, 0, stream>>>(
      attno, WprojT, b_proj, x1, x2, nullptr, M, 1024, 1024);
  k_layernorm_bf16<<<M, blk, 0, stream>>>(x2, ln2_g, ln2_b, x3);
  // FC: dbuf 128^2, grid 32x32, EPI2 gelu
  k_gemm_bt<2><<<dim3(4096 / 128, M / 128), blk, 0, stream>>>(
      x3, WfcT, b_fc, nullptr, hbuf, nullptr, M, 4096, 1024);
  k_gemm_bt<1><<<dim3(1024 / 128, M / 128), blk, 0, stream>>>(
      hbuf, WmlpT, b_mlp, x3, d_out, nullptr, M, 1024, 4096);
}

// Round 11
// 266.439 us; speedup vs baseline: 1.0427x; 1.0427x over previous
//
#include <hip/hip_runtime.h>
#include <cstdint>

typedef __attribute__((ext_vector_type(8))) short bf16x8;
typedef __attribute__((ext_vector_type(4))) float f32x4;
typedef __attribute__((ext_vector_type(16))) float f32x16;
typedef __attribute__((ext_vector_type(4))) unsigned short u16x4;
typedef __attribute__((ext_vector_type(4))) unsigned int u32x4;
typedef unsigned short u16;

#define LOG2E 1.44269504088896340736f

__device__ __forceinline__ u16 f2bf(float f) {
  unsigned u = __builtin_bit_cast(unsigned, f);
  u += 0x7FFFu + ((u >> 16) & 1u);
  return (u16)(u >> 16);
}
__device__ __forceinline__ float bf2f(u16 h) {
  return __builtin_bit_cast(float, ((unsigned)h) << 16);
}

#define GLOAD_LDS16(g, l)                                                              \
  __builtin_amdgcn_global_load_lds((const __attribute__((address_space(1))) void*)(g), \
                                   (__attribute__((address_space(3))) void*)(l), 16, 0, 0)

// ---------------- weight transpose f32[K][N] -> bf16[N][K] ----------------
__global__ __launch_bounds__(256) void k_transpose_bf16(
    const float* __restrict__ W, u16* __restrict__ Wt, int K, int N) {
  __shared__ float tile[32][33];
  const int tid = threadIdx.x;
  const int tx = tid & 31, ty = tid >> 5;
  const int n0 = blockIdx.x * 32, k0 = blockIdx.y * 32;
#pragma unroll
  for (int i = 0; i < 32; i += 8)
    tile[ty + i][tx] = W[(size_t)(k0 + ty + i) * N + n0 + tx];
  __syncthreads();
#pragma unroll
  for (int i = 0; i < 32; i += 8)
    Wt[(size_t)(n0 + ty + i) * K + k0 + tx] = f2bf(tile[tx][ty + i]);
}

// ---------------- LayerNorm f32[row][1024] -> bf16 ----------------
__global__ __launch_bounds__(256) void k_layernorm_bf16(
    const float* __restrict__ x, const float* __restrict__ g,
    const float* __restrict__ b, u16* __restrict__ y) {
  const int row = blockIdx.x, tid = threadIdx.x;
  const float4 v = ((const float4*)(x + (size_t)row * 1024))[tid];
  float s = v.x + v.y + v.z + v.w;
#pragma unroll
  for (int m = 1; m < 64; m <<= 1) s += __shfl_xor(s, m);
  __shared__ float ps[8];
  if ((tid & 63) == 0) ps[tid >> 6] = s;
  __syncthreads();
  const float mean = (ps[0] + ps[1] + ps[2] + ps[3]) * (1.0f / 1024.0f);
  const float d0 = v.x - mean, d1 = v.y - mean, d2 = v.z - mean, d3 = v.w - mean;
  float s2 = d0 * d0 + d1 * d1 + d2 * d2 + d3 * d3;
#pragma unroll
  for (int m = 1; m < 64; m <<= 1) s2 += __shfl_xor(s2, m);
  if ((tid & 63) == 0) ps[4 + (tid >> 6)] = s2;
  __syncthreads();
  const float var = (ps[4] + ps[5] + ps[6] + ps[7]) * (1.0f / 1024.0f);
  const float rstd = rsqrtf(var + 1e-5f);
  const float4 gv = ((const float4*)g)[tid];
  const float4 bv = ((const float4*)b)[tid];
  u16x4 o;
  o[0] = f2bf(d0 * rstd * gv.x + bv.x);
  o[1] = f2bf(d1 * rstd * gv.y + bv.y);
  o[2] = f2bf(d2 * rstd * gv.z + bv.z);
  o[3] = f2bf(d3 * rstd * gv.w + bv.w);
  *(u16x4*)(y + (size_t)row * 1024 + tid * 4) = o;
}

__device__ __forceinline__ float gelu_f(float x) {
  const float u = 0.7978845608028654f * (x + 0.044715f * x * x * x);
  const float e = exp2f(u * 2.8853900817779268f);  // e^{2u}
  const float t = 1.0f - 2.0f / (e + 1.0f);        // tanh(u)
  return 0.5f * x * (1.0f + t);
}

// ---------------- 128x128 GEMM, double-buffered (the proven workhorse) ----------
template <int EPI>
__global__ __launch_bounds__(256, 2) void k_gemm_bt(
    const u16* __restrict__ A, const u16* __restrict__ Bt,
    const float* __restrict__ bias, const u16* __restrict__ resid,
    void* __restrict__ out, u16* __restrict__ vt, int M, int N, int K) {
  __shared__ u16 As[2][128 * 64];
  __shared__ u16 Bs[2][128 * 64];
  const int tid = threadIdx.x;
  const int rowBase = blockIdx.y * 128, colBase = blockIdx.x * 128;
  const int w = tid >> 6, l = tid & 63;
  const int wm = w >> 1, wn = w & 1;
  const int lrow = l & 15, lg = l >> 4;
  const int srow = tid >> 3, sslot = tid & 7;

  const f32x4 fz = {0.f, 0.f, 0.f, 0.f};
  f32x4 acc[4][4];
#pragma unroll
  for (int m = 0; m < 4; m++)
#pragma unroll
    for (int n = 0; n < 4; n++) acc[m][n] = fz;

  const int NT = K >> 6;
  auto STAGE = [&](int b, int kt) {
#pragma unroll
    for (int i = 0; i < 4; i++) {
      const int r = srow + 32 * i;
      const int gs = sslot ^ (r & 7);
      GLOAD_LDS16(A + (size_t)(rowBase + r) * K + kt * 64 + gs * 8,
                  (char*)As[b] + i * 4096 + tid * 16);
      GLOAD_LDS16(Bt + (size_t)(colBase + r) * K + kt * 64 + gs * 8,
                  (char*)Bs[b] + i * 4096 + tid * 16);
    }
  };

  STAGE(0, 0);
  for (int kt = 0; kt < NT; ++kt) {
    const int buf = kt & 1;
    if (kt + 1 < NT) {
      STAGE(buf ^ 1, kt + 1);
      asm volatile("s_waitcnt vmcnt(8)" ::: "memory");
    } else {
      asm volatile("s_waitcnt vmcnt(0)" ::: "memory");
    }
    __builtin_amdgcn_s_barrier();
    const char* Ab = (const char*)As[buf];
    const char* Bb = (const char*)Bs[buf];
#pragma unroll
    for (int kc = 0; kc < 2; kc++) {
      bf16x8 av[4], bv[4];
#pragma unroll
      for (int m = 0; m < 4; m++) {
        const int r = wm * 64 + m * 16 + lrow;
        const int sl = (kc * 4 + lg) ^ (r & 7);
        av[m] = *(const bf16x8*)(Ab + r * 128 + sl * 16);
      }
#pragma unroll
      for (int n = 0; n < 4; n++) {
        const int r = wn * 64 + n * 16 + lrow;
        const int sl = (kc * 4 + lg) ^ (r & 7);
        bv[n] = *(const bf16x8*)(Bb + r * 128 + sl * 16);
      }
#pragma unroll
      for (int m = 0; m < 4; m++)
#pragma unroll
        for (int n = 0; n < 4; n++)
          acc[m][n] = __builtin_amdgcn_mfma_f32_16x16x32_bf16(av[m], bv[n], acc[m][n], 0, 0, 0);
    }
    __builtin_amdgcn_s_barrier();
  }
#pragma unroll
  for (int n = 0; n < 4; n++) {
    const int col = colBase + wn * 64 + n * 16 + lrow;
    const float bval = bias[col];
#pragma unroll
    for (int m = 0; m < 4; m++) {
      const int row0 = rowBase + wm * 64 + m * 16 + lg * 4;
      if (EPI == 3 && col >= 2048) {
        const int c2 = col - 2048;
        const int hh = c2 >> 6, dd = c2 & 63;
        const int bat = row0 >> 11, tok0 = row0 & 2047;
        u16x4 pk;
#pragma unroll
        for (int r = 0; r < 4; r++) pk[r] = f2bf(acc[m][n][r] + bval);
        *(u16x4*)(vt + ((size_t)(bat * 16 + hh) * 64 + dd) * 2048 + tok0) = pk;
      } else if (EPI == 3) {
#pragma unroll
        for (int r = 0; r < 4; r++)
          ((u16*)out)[(size_t)(row0 + r) * 2048 + col] = f2bf(acc[m][n][r] + bval);
      } else {
#pragma unroll
        for (int r = 0; r < 4; r++) {
          const size_t idx = (size_t)(row0 + r) * N + col;
          float v = acc[m][n][r] + bval;
          if (EPI == 0) {
            ((u16*)out)[idx] = f2bf(v);
          } else if (EPI == 2) {
            ((u16*)out)[idx] = f2bf(gelu_f(v));
          } else {
            v += bf2f(resid[idx]);
            ((float*)out)[idx] = v;
          }
        }
      }
    }
  }
}

// ---------------- causal flash attention v5: swapped-QK^T, in-register softmax ----
// 4 warps x 32 q-rows (QBLK=128), KVBLK=64, 32x32x16 MFMA.
// S^T = mfma(A=K, B=Q): lane holds P[q=l&31][32 keys] across sv0/sv1 regs
//   (key_local = (reg&3)+8*(reg>>2)+4*(l>>5)) -> softmax: 31 in-lane fmax + 1 shfl.
// PV: O^T = mfma(A=V^T from VT-LDS, B=P^T built in-register via cvt_pk+shfl_xor(32)).
// No block barrier in k-loop except staging sync. T13 defer-max. LPT grid 512.
__global__ __launch_bounds__(256, 2) void k_attention(
    const u16* __restrict__ qk, const u16* __restrict__ VT, u16* __restrict__ out) {
  const int S = 2048, E2 = 2048;
  const int bid = blockIdx.x;
  const int qt = 15 - (bid >> 5);  // LPT: heaviest q-tiles first
  const int bh = bid & 31;
  const int bat = bh >> 4, h = bh & 15;
  const u16* base = qk + (size_t)bat * S * E2;
  const u16* kbase = base + 1024 + h * 64;
  const u16* vbase = VT + (size_t)bh * 64 * S;  // [d][tok]
  const int tid = threadIdx.x, w = tid >> 6, l = tid & 63;
  const int l31 = l & 31, lh = l >> 5;
  __shared__ u16 Ks[2][64 * 64];  // [key][d-slot], XOR-swizzled content
  __shared__ u16 Vs[2][64 * 64];  // [d][tok-slot], XOR-swizzled content
  const int srow = tid >> 3;
  const int gs = (tid & 7) ^ (srow & 7);
  const float sc = 0.125f * LOG2E;
  const float RTHR = 8.0f / sc;  // defer-max threshold (raw-score units)

  auto STAGE = [&](int bufi, int kb) {
#pragma unroll
    for (int round = 0; round < 2; round++) {
      const int r = srow + 32 * round;
      GLOAD_LDS16(kbase + (size_t)(kb + r) * E2 + gs * 8, (char*)Ks[bufi] + round * 4096 + tid * 16);
      GLOAD_LDS16(vbase + (size_t)r * S + kb + gs * 8, (char*)Vs[bufi] + round * 4096 + tid * 16);
    }
  };

  const int wq0 = qt * 128 + w * 32;
  const int qg = wq0 + l31;       // this lane's query row (global)
  const int tdiag = wq0 >> 6;     // last tile this warp needs (partial/diagonal)
  const int nkt = 2 * qt + 2;

  // Q as MFMA B-operand: lane l holds Q[q=l&31][d = s*16 + lh*8 .. +8]
  bf16x8 qf[4];
#pragma unroll
  for (int s = 0; s < 4; s++)
    qf[s] = *(const bf16x8*)(base + (size_t)qg * E2 + h * 64 + s * 16 + lh * 8);

  f32x16 o0, o1;  // O^T accumulators (d-blocks 0,1): row=d_local, col=q
#pragma unroll
  for (int r = 0; r < 16; r++) { o0[r] = 0.f; o1[r] = 0.f; }
  float mrow = -1e30f, lsum = 0.f;

  STAGE(0, 0);
  __syncthreads();

  for (int t = 0; t < nkt; t++) {
    const int cur = t & 1;
    const int kb = t * 64;
    if (t + 1 < nkt) STAGE(cur ^ 1, kb + 64);  // prefetch; drains at loop-end barrier
    if (t <= tdiag) {  // wave-uniform: skip tiles past this warp's diagonal
      const u16* Kc = Ks[cur];
      const u16* Vc = Vs[cur];

      // ---- S^T = K Q^T (two key-halves) ----
      f32x16 sv0, sv1;
#pragma unroll
      for (int r = 0; r < 16; r++) { sv0[r] = 0.f; sv1[r] = 0.f; }
#pragma unroll
      for (int s = 0; s < 4; s++) {
        const int row0 = l31, row1 = 32 + l31;
        const int sl = s * 2 + lh;
        const bf16x8 k0 = *(const bf16x8*)(Kc + row0 * 64 + ((sl ^ (row0 & 7)) * 8));
        const bf16x8 k1 = *(const bf16x8*)(Kc + row1 * 64 + ((sl ^ (row1 & 7)) * 8));
        sv0 = __builtin_amdgcn_mfma_f32_32x32x16_bf16(k0, qf[s], sv0, 0, 0, 0);
        sv1 = __builtin_amdgcn_mfma_f32_32x32x16_bf16(k1, qf[s], sv1, 0, 0, 0);
      }

      // ---- causal mask (diagonal tile only) ----
      if (t == tdiag) {
#pragma unroll
        for (int reg = 0; reg < 16; reg++) {
          const int kl = (reg & 3) + 8 * (reg >> 2) + 4 * lh;
          if (kb + kl > qg) sv0[reg] = -1e30f;
          if (kb + 32 + kl > qg) sv1[reg] = -1e30f;
        }
      }

      // ---- row max: 31 in-lane fmax + 1 cross-half shfl ----
      float tmax = sv0[0];
#pragma unroll
      for (int reg = 1; reg < 16; reg++) tmax = fmaxf(tmax, sv0[reg]);
#pragma unroll
      for (int reg = 0; reg < 16; reg++) tmax = fmaxf(tmax, sv1[reg]);
      tmax = fmaxf(tmax, __shfl_xor(tmax, 32));

      // ---- defer-max online update (T13) ----
      if (!__all(tmax - mrow <= RTHR)) {
        const float mnew = fmaxf(mrow, tmax);
        const float corr = exp2f((mrow - mnew) * sc);
        lsum *= corr;
#pragma unroll
        for (int reg = 0; reg < 16; reg++) { o0[reg] *= corr; o1[reg] *= corr; }
        mrow = mnew;
      }
      const float msc = mrow * sc;

      // ---- P = exp2(s*sc - m*sc), row-sum ----
      float p0[16], p1[16];
      float rsum = 0.f;
#pragma unroll
      for (int reg = 0; reg < 16; reg++) {
        p0[reg] = exp2f(fmaf(sv0[reg], sc, -msc));
        p1[reg] = exp2f(fmaf(sv1[reg], sc, -msc));
        rsum += p0[reg] + p1[reg];
      }
      rsum += __shfl_xor(rsum, 32);
      lsum += rsum;

      // ---- pack P pairs to bf16x2 words, exchange lane-halves ----
      unsigned pk0[8], pk1[8], ex0[8], ex1[8];
#pragma unroll
      for (int j = 0; j < 8; j++) {
        asm("v_cvt_pk_bf16_f32 %0, %1, %2" : "=v"(pk0[j]) : "v"(p0[2 * j]), "v"(p0[2 * j + 1]));
        asm("v_cvt_pk_bf16_f32 %0, %1, %2" : "=v"(pk1[j]) : "v"(p1[2 * j]), "v"(p1[2 * j + 1]));
        ex0[j] = (unsigned)__shfl_xor((int)pk0[j], 32);
        ex1[j] = (unsigned)__shfl_xor((int)pk1[j], 32);
      }
      const bool lo = (lh == 0);

      // ---- O^T += V^T P^T  (2 d-blocks x 4 k-slices) ----
#pragma unroll
      for (int kh = 0; kh < 2; kh++) {
#pragma unroll
        for (int sl2 = 0; sl2 < 2; sl2++) {
          const int ks = kh * 2 + sl2;
          const unsigned* pk = kh ? pk1 : pk0;
          const unsigned* ex = kh ? ex1 : ex0;
          const int j0 = sl2 * 4;
          const unsigned b0 = lo ? pk[j0 + 0] : ex[j0 + 2];
          const unsigned b1 = lo ? pk[j0 + 1] : ex[j0 + 3];
          const unsigned b2 = lo ? ex[j0 + 0] : pk[j0 + 2];
          const unsigned b3 = lo ? ex[j0 + 1] : pk[j0 + 3];
          const u32x4 pbu = {b0, b1, b2, b3};
          const bf16x8 pb = __builtin_bit_cast(bf16x8, pbu);
          const int sl = ks * 2 + lh;
          const int r0 = l31, r1 = 32 + l31;
          const bf16x8 v0 = *(const bf16x8*)(Vc + r0 * 64 + ((sl ^ (r0 & 7)) * 8));
          const bf16x8 v1 = *(const bf16x8*)(Vc + r1 * 64 + ((sl ^ (r1 & 7)) * 8));
          o0 = __builtin_amdgcn_mfma_f32_32x32x16_bf16(v0, pb, o0, 0, 0, 0);
          o1 = __builtin_amdgcn_mfma_f32_32x32x16_bf16(v1, pb, o1, 0, 0, 0);
        }
      }
    }
    __syncthreads();  // drains prefetch (vmcnt 0) + fences LDS buffer reuse
  }

  // ---- epilogue: O^T/lsum -> out[tok][h*64+d] ----
  const float inv = 1.0f / lsum;
  const size_t orow = (size_t)(bat * S + qg) * 1024 + h * 64;
#pragma unroll
  for (int g = 0; g < 4; g++) {
    u16x4 s0, s1;
#pragma unroll
    for (int r = 0; r < 4; r++) {
      s0[r] = f2bf(o0[4 * g + r] * inv);
      s1[r] = f2bf(o1[4 * g + r] * inv);
    }
    const int d0 = 8 * g + 4 * lh;
    *(u16x4*)(out + orow + d0) = s0;
    *(u16x4*)(out + orow + 32 + d0) = s1;
  }
}

// ---------------- host launch ----------------
extern "C" void kernel_launch(void* const* d_in, const int* in_sizes, int n_in,
                              void* d_out, int out_size, void* d_ws, size_t ws_size,
                              hipStream_t stream) {
  (void)in_sizes; (void)n_in; (void)out_size; (void)ws_size;
  const float* x      = (const float*)d_in[0];
  const float* ln1_g  = (const float*)d_in[1];
  const float* ln1_b  = (const float*)d_in[2];
  const float* W_attn = (const float*)d_in[3];
  const float* b_attn = (const float*)d_in[4];
  const float* W_proj = (const float*)d_in[5];
  const float* b_proj = (const float*)d_in[6];
  const float* ln2_g  = (const float*)d_in[7];
  const float* ln2_b  = (const float*)d_in[8];
  const float* W_fc   = (const float*)d_in[9];
  const float* b_fc   = (const float*)d_in[10];
  const float* W_mlp  = (const float*)d_in[11];
  const float* b_mlp  = (const float*)d_in[12];

  const int M = 4096;  // B*S = 2*2048
  char* ws = (char*)d_ws;
  size_t off = 0;
  auto alloc = [&](size_t bytes) {
    void* p = ws + off;
    off += (bytes + 255) & ~(size_t)255;
    return p;
  };
  u16* WattnT = (u16*)alloc((size_t)3072 * 1024 * 2);
  u16* WprojT = (u16*)alloc((size_t)1024 * 1024 * 2);
  u16* WfcT   = (u16*)alloc((size_t)4096 * 1024 * 2);
  u16* WmlpT  = (u16*)alloc((size_t)1024 * 4096 * 2);
  u16* x1     = (u16*)alloc((size_t)M * 1024 * 2);
  u16* qkb    = (u16*)alloc((size_t)M * 2048 * 2);        // Q|K only
  u16* VT     = (u16*)alloc((size_t)32 * 64 * 2048 * 2);  // [b*h][d][tok]
  u16* attno  = (u16*)alloc((size_t)M * 1024 * 2);
  float* x2   = (float*)alloc((size_t)M * 1024 * 4);
  u16* x3     = (u16*)alloc((size_t)M * 1024 * 2);
  u16* hbuf   = (u16*)alloc((size_t)M * 4096 * 2);

  const dim3 blk(256);
  k_transpose_bf16<<<dim3(3072 / 32, 1024 / 32), blk, 0, stream>>>(W_attn, WattnT, 1024, 3072);
  k_transpose_bf16<<<dim3(1024 / 32, 1024 / 32), blk, 0, stream>>>(W_proj, WprojT, 1024, 1024);
  k_transpose_bf16<<<dim3(4096 / 32, 1024 / 32), blk, 0, stream>>>(W_fc, WfcT, 1024, 4096);
  k_transpose_bf16<<<dim3(1024 / 32, 4096 / 32), blk, 0, stream>>>(W_mlp, WmlpT, 4096, 1024);

  k_layernorm_bf16<<<M, blk, 0, stream>>>(x, ln1_g, ln1_b, x1);
  // QKV: dbuf 128^2, grid 24x32, EPI3 split epilogue (Q|K + transposed V)
  k_gemm_bt<3><<<dim3(3072 / 128, M / 128), blk, 0, stream>>>(
      x1, WattnT, b_attn, nullptr, qkb, VT, M, 3072, 1024);
  k_attention<<<dim3(512), blk, 0, stream>>>(qkb, VT, attno);
  k_gemm_bt<1><<<dim3(1024 / 128, M / 128), blk, 0, stream>>>(
      attno, WprojT, b_proj, x1, x2, nullptr, M, 1024, 1024);
  k_layernorm_bf16<<<M, blk, 0, stream>>>(x2, ln2_g, ln2_b, x3);
  // FC: dbuf 128^2, grid 32x32, EPI2 gelu
  k_gemm_bt<2><<<dim3(4096 / 128, M / 128), blk, 0, stream>>>(
      x3, WfcT, b_fc, nullptr, hbuf, nullptr, M, 4096, 1024);
  k_gemm_bt<1><<<dim3(1024 / 128, M / 128), blk, 0, stream>>>(
      hbuf, WmlpT, b_mlp, x3, d_out, nullptr, M, 1024, 4096);
}

// Round 12
// 252.624 us; speedup vs baseline: 1.0997x; 1.0547x over previous
//
#include <hip/hip_runtime.h>
#include <cstdint>

typedef __attribute__((ext_vector_type(8))) short bf16x8;
typedef __attribute__((ext_vector_type(4))) float f32x4;
typedef __attribute__((ext_vector_type(16))) float f32x16;
typedef __attribute__((ext_vector_type(4))) unsigned short u16x4;
typedef __attribute__((ext_vector_type(4))) unsigned int u32x4;
typedef unsigned short u16;

#define LOG2E 1.44269504088896340736f

__device__ __forceinline__ u16 f2bf(float f) {
  unsigned u = __builtin_bit_cast(unsigned, f);
  u += 0x7FFFu + ((u >> 16) & 1u);
  return (u16)(u >> 16);
}
__device__ __forceinline__ float bf2f(u16 h) {
  return __builtin_bit_cast(float, ((unsigned)h) << 16);
}

#define GLOAD_LDS16(g, l)                                                              \
  __builtin_amdgcn_global_load_lds((const __attribute__((address_space(1))) void*)(g), \
                                   (__attribute__((address_space(3))) void*)(l), 16, 0, 0)

// ---------------- weight transpose f32[K][N] -> bf16[N][K] ----------------
__global__ __launch_bounds__(256) void k_transpose_bf16(
    const float* __restrict__ W, u16* __restrict__ Wt, int K, int N) {
  __shared__ float tile[32][33];
  const int tid = threadIdx.x;
  const int tx = tid & 31, ty = tid >> 5;
  const int n0 = blockIdx.x * 32, k0 = blockIdx.y * 32;
#pragma unroll
  for (int i = 0; i < 32; i += 8)
    tile[ty + i][tx] = W[(size_t)(k0 + ty + i) * N + n0 + tx];
  __syncthreads();
#pragma unroll
  for (int i = 0; i < 32; i += 8)
    Wt[(size_t)(n0 + ty + i) * K + k0 + tx] = f2bf(tile[tx][ty + i]);
}

// ---------------- LayerNorm f32[row][1024] -> bf16 ----------------
__global__ __launch_bounds__(256) void k_layernorm_bf16(
    const float* __restrict__ x, const float* __restrict__ g,
    const float* __restrict__ b, u16* __restrict__ y) {
  const int row = blockIdx.x, tid = threadIdx.x;
  const float4 v = ((const float4*)(x + (size_t)row * 1024))[tid];
  float s = v.x + v.y + v.z + v.w;
#pragma unroll
  for (int m = 1; m < 64; m <<= 1) s += __shfl_xor(s, m);
  __shared__ float ps[8];
  if ((tid & 63) == 0) ps[tid >> 6] = s;
  __syncthreads();
  const float mean = (ps[0] + ps[1] + ps[2] + ps[3]) * (1.0f / 1024.0f);
  const float d0 = v.x - mean, d1 = v.y - mean, d2 = v.z - mean, d3 = v.w - mean;
  float s2 = d0 * d0 + d1 * d1 + d2 * d2 + d3 * d3;
#pragma unroll
  for (int m = 1; m < 64; m <<= 1) s2 += __shfl_xor(s2, m);
  if ((tid & 63) == 0) ps[4 + (tid >> 6)] = s2;
  __syncthreads();
  const float var = (ps[4] + ps[5] + ps[6] + ps[7]) * (1.0f / 1024.0f);
  const float rstd = rsqrtf(var + 1e-5f);
  const float4 gv = ((const float4*)g)[tid];
  const float4 bv = ((const float4*)b)[tid];
  u16x4 o;
  o[0] = f2bf(d0 * rstd * gv.x + bv.x);
  o[1] = f2bf(d1 * rstd * gv.y + bv.y);
  o[2] = f2bf(d2 * rstd * gv.z + bv.z);
  o[3] = f2bf(d3 * rstd * gv.w + bv.w);
  *(u16x4*)(y + (size_t)row * 1024 + tid * 4) = o;
}

__device__ __forceinline__ float gelu_f(float x) {
  const float u = 0.7978845608028654f * (x + 0.044715f * x * x * x);
  const float e = exp2f(u * 2.8853900817779268f);  // e^{2u}
  const float t = 1.0f - 2.0f / (e + 1.0f);        // tanh(u)
  return 0.5f * x * (1.0f + t);
}

// ---------------- 128xBN GEMM, single-buffered m97 structure ----------------
// BN=128: 2x2 waves (64x64 each), 32KB LDS -> 4-5 blocks/CU where grid allows.
// BN=64 : 4x1 waves (32x64 each), 24KB LDS -> doubles grid for narrow N.
// 1-D grid with bijective XCD swizzle (gridDim.x % 8 == 0 guaranteed by caller).
// EPI 0: bf16  EPI 1: f32 + bf16 residual  EPI 2: bf16+gelu  EPI 3: qkv split
template <int EPI, int BN>
__global__ __launch_bounds__(256, 4) void k_gemm_bt(
    const u16* __restrict__ A, const u16* __restrict__ Bt,
    const float* __restrict__ bias, const u16* __restrict__ resid,
    void* __restrict__ out, u16* __restrict__ vt, int M, int N, int K, int nbx) {
  constexpr int BM = 128;
  __shared__ u16 As[BM * 64];
  __shared__ u16 Bs[BN * 64];
  const int tid = threadIdx.x;
  const int wg = ((blockIdx.x & 7) * (gridDim.x >> 3)) + (blockIdx.x >> 3);
  const int bx = wg % nbx, by = wg / nbx;
  const int rowBase = by * BM, colBase = bx * BN;
  const int w = tid >> 6, l = tid & 63;
  const int wm = (BN == 128) ? (w >> 1) : w;
  const int wn = (BN == 128) ? (w & 1) : 0;
  constexpr int MR = (BN == 128) ? 4 : 2;       // m-fragments per wave
  constexpr int WROWS = (BN == 128) ? 64 : 32;  // rows per wave
  const int lrow = l & 15, lg = l >> 4;
  const int srow = tid >> 3, sslot = tid & 7;

  const f32x4 fz = {0.f, 0.f, 0.f, 0.f};
  f32x4 acc[MR][4];
#pragma unroll
  for (int m = 0; m < MR; m++)
#pragma unroll
    for (int n = 0; n < 4; n++) acc[m][n] = fz;

  const int NT = K >> 6;
  for (int kt = 0; kt < NT; ++kt) {
#pragma unroll
    for (int i = 0; i < BM / 32; i++) {
      const int r = srow + 32 * i;
      const int gs = sslot ^ (r & 7);  // inverse-swizzled source, linear LDS dest
      GLOAD_LDS16(A + (size_t)(rowBase + r) * K + kt * 64 + gs * 8,
                  (char*)As + i * 4096 + tid * 16);
    }
#pragma unroll
    for (int i = 0; i < BN / 32; i++) {
      const int r = srow + 32 * i;
      const int gs = sslot ^ (r & 7);
      GLOAD_LDS16(Bt + (size_t)(colBase + r) * K + kt * 64 + gs * 8,
                  (char*)Bs + i * 4096 + tid * 16);
    }
    __syncthreads();  // drains global_load_lds (vmcnt 0) + staging visible block-wide
#pragma unroll
    for (int kc = 0; kc < 2; kc++) {
      bf16x8 av[MR], bv[4];
#pragma unroll
      for (int m = 0; m < MR; m++) {
        const int r = wm * WROWS + m * 16 + lrow;
        const int sl = (kc * 4 + lg) ^ (r & 7);
        av[m] = *(const bf16x8*)((const char*)As + r * 128 + sl * 16);
      }
#pragma unroll
      for (int n = 0; n < 4; n++) {
        const int r = wn * 64 + n * 16 + lrow;
        const int sl = (kc * 4 + lg) ^ (r & 7);
        bv[n] = *(const bf16x8*)((const char*)Bs + r * 128 + sl * 16);
      }
#pragma unroll
      for (int m = 0; m < MR; m++)
#pragma unroll
        for (int n = 0; n < 4; n++)
          acc[m][n] = __builtin_amdgcn_mfma_f32_16x16x32_bf16(av[m], bv[n], acc[m][n], 0, 0, 0);
    }
    __syncthreads();  // all waves done reading before next stage overwrites
  }
#pragma unroll
  for (int n = 0; n < 4; n++) {
    const int col = colBase + wn * 64 + n * 16 + lrow;
    const float bval = bias[col];
#pragma unroll
    for (int m = 0; m < MR; m++) {
      const int row0 = rowBase + wm * WROWS + m * 16 + lg * 4;
      if (EPI == 3 && col >= 2048) {
        const int c2 = col - 2048;
        const int hh = c2 >> 6, dd = c2 & 63;
        const int bat = row0 >> 11, tok0 = row0 & 2047;
        u16x4 pk;
#pragma unroll
        for (int r = 0; r < 4; r++) pk[r] = f2bf(acc[m][n][r] + bval);
        *(u16x4*)(vt + ((size_t)(bat * 16 + hh) * 64 + dd) * 2048 + tok0) = pk;
      } else if (EPI == 3) {
#pragma unroll
        for (int r = 0; r < 4; r++)
          ((u16*)out)[(size_t)(row0 + r) * 2048 + col] = f2bf(acc[m][n][r] + bval);
      } else {
#pragma unroll
        for (int r = 0; r < 4; r++) {
          const size_t idx = (size_t)(row0 + r) * N + col;
          float v = acc[m][n][r] + bval;
          if (EPI == 0) {
            ((u16*)out)[idx] = f2bf(v);
          } else if (EPI == 2) {
            ((u16*)out)[idx] = f2bf(gelu_f(v));
          } else {
            v += bf2f(resid[idx]);
            ((float*)out)[idx] = v;
          }
        }
      }
    }
  }
}

// ---------------- causal flash attention v5 (unchanged from R11) ----------
__global__ __launch_bounds__(256, 2) void k_attention(
    const u16* __restrict__ qk, const u16* __restrict__ VT, u16* __restrict__ out) {
  const int S = 2048, E2 = 2048;
  const int bid = blockIdx.x;
  const int qt = 15 - (bid >> 5);  // LPT: heaviest q-tiles first
  const int bh = bid & 31;
  const int bat = bh >> 4, h = bh & 15;
  const u16* base = qk + (size_t)bat * S * E2;
  const u16* kbase = base + 1024 + h * 64;
  const u16* vbase = VT + (size_t)bh * 64 * S;  // [d][tok]
  const int tid = threadIdx.x, w = tid >> 6, l = tid & 63;
  const int l31 = l & 31, lh = l >> 5;
  __shared__ u16 Ks[2][64 * 64];
  __shared__ u16 Vs[2][64 * 64];
  const int srow = tid >> 3;
  const int gs = (tid & 7) ^ (srow & 7);
  const float sc = 0.125f * LOG2E;
  const float RTHR = 8.0f / sc;

  auto STAGE = [&](int bufi, int kb) {
#pragma unroll
    for (int round = 0; round < 2; round++) {
      const int r = srow + 32 * round;
      GLOAD_LDS16(kbase + (size_t)(kb + r) * E2 + gs * 8, (char*)Ks[bufi] + round * 4096 + tid * 16);
      GLOAD_LDS16(vbase + (size_t)r * S + kb + gs * 8, (char*)Vs[bufi] + round * 4096 + tid * 16);
    }
  };

  const int wq0 = qt * 128 + w * 32;
  const int qg = wq0 + l31;
  const int tdiag = wq0 >> 6;
  const int nkt = 2 * qt + 2;

  bf16x8 qf[4];
#pragma unroll
  for (int s = 0; s < 4; s++)
    qf[s] = *(const bf16x8*)(base + (size_t)qg * E2 + h * 64 + s * 16 + lh * 8);

  f32x16 o0, o1;
#pragma unroll
  for (int r = 0; r < 16; r++) { o0[r] = 0.f; o1[r] = 0.f; }
  float mrow = -1e30f, lsum = 0.f;

  STAGE(0, 0);
  __syncthreads();

  for (int t = 0; t < nkt; t++) {
    const int cur = t & 1;
    const int kb = t * 64;
    if (t + 1 < nkt) STAGE(cur ^ 1, kb + 64);
    if (t <= tdiag) {
      const u16* Kc = Ks[cur];
      const u16* Vc = Vs[cur];

      f32x16 sv0, sv1;
#pragma unroll
      for (int r = 0; r < 16; r++) { sv0[r] = 0.f; sv1[r] = 0.f; }
#pragma unroll
      for (int s = 0; s < 4; s++) {
        const int row0 = l31, row1 = 32 + l31;
        const int sl = s * 2 + lh;
        const bf16x8 k0 = *(const bf16x8*)(Kc + row0 * 64 + ((sl ^ (row0 & 7)) * 8));
        const bf16x8 k1 = *(const bf16x8*)(Kc + row1 * 64 + ((sl ^ (row1 & 7)) * 8));
        sv0 = __builtin_amdgcn_mfma_f32_32x32x16_bf16(k0, qf[s], sv0, 0, 0, 0);
        sv1 = __builtin_amdgcn_mfma_f32_32x32x16_bf16(k1, qf[s], sv1, 0, 0, 0);
      }

      if (t == tdiag) {
#pragma unroll
        for (int reg = 0; reg < 16; reg++) {
          const int kl = (reg & 3) + 8 * (reg >> 2) + 4 * lh;
          if (kb + kl > qg) sv0[reg] = -1e30f;
          if (kb + 32 + kl > qg) sv1[reg] = -1e30f;
        }
      }

      float tmax = sv0[0];
#pragma unroll
      for (int reg = 1; reg < 16; reg++) tmax = fmaxf(tmax, sv0[reg]);
#pragma unroll
      for (int reg = 0; reg < 16; reg++) tmax = fmaxf(tmax, sv1[reg]);
      tmax = fmaxf(tmax, __shfl_xor(tmax, 32));

      if (!__all(tmax - mrow <= RTHR)) {
        const float mnew = fmaxf(mrow, tmax);
        const float corr = exp2f((mrow - mnew) * sc);
        lsum *= corr;
#pragma unroll
        for (int reg = 0; reg < 16; reg++) { o0[reg] *= corr; o1[reg] *= corr; }
        mrow = mnew;
      }
      const float msc = mrow * sc;

      float p0[16], p1[16];
      float rsum = 0.f;
#pragma unroll
      for (int reg = 0; reg < 16; reg++) {
        p0[reg] = exp2f(fmaf(sv0[reg], sc, -msc));
        p1[reg] = exp2f(fmaf(sv1[reg], sc, -msc));
        rsum += p0[reg] + p1[reg];
      }
      rsum += __shfl_xor(rsum, 32);
      lsum += rsum;

      unsigned pk0[8], pk1[8], ex0[8], ex1[8];
#pragma unroll
      for (int j = 0; j < 8; j++) {
        asm("v_cvt_pk_bf16_f32 %0, %1, %2" : "=v"(pk0[j]) : "v"(p0[2 * j]), "v"(p0[2 * j + 1]));
        asm("v_cvt_pk_bf16_f32 %0, %1, %2" : "=v"(pk1[j]) : "v"(p1[2 * j]), "v"(p1[2 * j + 1]));
        ex0[j] = (unsigned)__shfl_xor((int)pk0[j], 32);
        ex1[j] = (unsigned)__shfl_xor((int)pk1[j], 32);
      }
      const bool lo = (lh == 0);

#pragma unroll
      for (int kh = 0; kh < 2; kh++) {
#pragma unroll
        for (int sl2 = 0; sl2 < 2; sl2++) {
          const int ks = kh * 2 + sl2;
          const unsigned* pk = kh ? pk1 : pk0;
          const unsigned* ex = kh ? ex1 : ex0;
          const int j0 = sl2 * 4;
          const unsigned b0 = lo ? pk[j0 + 0] : ex[j0 + 2];
          const unsigned b1 = lo ? pk[j0 + 1] : ex[j0 + 3];
          const unsigned b2 = lo ? ex[j0 + 0] : pk[j0 + 2];
          const unsigned b3 = lo ? ex[j0 + 1] : pk[j0 + 3];
          const u32x4 pbu = {b0, b1, b2, b3};
          const bf16x8 pb = __builtin_bit_cast(bf16x8, pbu);
          const int sl = ks * 2 + lh;
          const int r0 = l31, r1 = 32 + l31;
          const bf16x8 v0 = *(const bf16x8*)(Vc + r0 * 64 + ((sl ^ (r0 & 7)) * 8));
          const bf16x8 v1 = *(const bf16x8*)(Vc + r1 * 64 + ((sl ^ (r1 & 7)) * 8));
          o0 = __builtin_amdgcn_mfma_f32_32x32x16_bf16(v0, pb, o0, 0, 0, 0);
          o1 = __builtin_amdgcn_mfma_f32_32x32x16_bf16(v1, pb, o1, 0, 0, 0);
        }
      }
    }
    __syncthreads();
  }

  const float inv = 1.0f / lsum;
  const size_t orow = (size_t)(bat * S + qg) * 1024 + h * 64;
#pragma unroll
  for (int g = 0; g < 4; g++) {
    u16x4 s0, s1;
#pragma unroll
    for (int r = 0; r < 4; r++) {
      s0[r] = f2bf(o0[4 * g + r] * inv);
      s1[r] = f2bf(o1[4 * g + r] * inv);
    }
    const int d0 = 8 * g + 4 * lh;
    *(u16x4*)(out + orow + d0) = s0;
    *(u16x4*)(out + orow + 32 + d0) = s1;
  }
}

// ---------------- host launch ----------------
extern "C" void kernel_launch(void* const* d_in, const int* in_sizes, int n_in,
                              void* d_out, int out_size, void* d_ws, size_t ws_size,
                              hipStream_t stream) {
  (void)in_sizes; (void)n_in; (void)out_size; (void)ws_size;
  const float* x      = (const float*)d_in[0];
  const float* ln1_g  = (const float*)d_in[1];
  const float* ln1_b  = (const float*)d_in[2];
  const float* W_attn = (const float*)d_in[3];
  const float* b_attn = (const float*)d_in[4];
  const float* W_proj = (const float*)d_in[5];
  const float* b_proj = (const float*)d_in[6];
  const float* ln2_g  = (const float*)d_in[7];
  const float* ln2_b  = (const float*)d_in[8];
  const float* W_fc   = (const float*)d_in[9];
  const float* b_fc   = (const float*)d_in[10];
  const float* W_mlp  = (const float*)d_in[11];
  const float* b_mlp  = (const float*)d_in[12];

  const int M = 4096;  // B*S = 2*2048
  char* ws = (char*)d_ws;
  size_t off = 0;
  auto alloc = [&](size_t bytes) {
    void* p = ws + off;
    off += (bytes + 255) & ~(size_t)255;
    return p;
  };
  u16* WattnT = (u16*)alloc((size_t)3072 * 1024 * 2);
  u16* WprojT = (u16*)alloc((size_t)1024 * 1024 * 2);
  u16* WfcT   = (u16*)alloc((size_t)4096 * 1024 * 2);
  u16* WmlpT  = (u16*)alloc((size_t)1024 * 4096 * 2);
  u16* x1     = (u16*)alloc((size_t)M * 1024 * 2);
  u16* qkb    = (u16*)alloc((size_t)M * 2048 * 2);        // Q|K only
  u16* VT     = (u16*)alloc((size_t)32 * 64 * 2048 * 2);  // [b*h][d][tok]
  u16* attno  = (u16*)alloc((size_t)M * 1024 * 2);
  float* x2   = (float*)alloc((size_t)M * 1024 * 4);
  u16* x3     = (u16*)alloc((size_t)M * 1024 * 2);
  u16* hbuf   = (u16*)alloc((size_t)M * 4096 * 2);

  const dim3 blk(256);
  k_transpose_bf16<<<dim3(3072 / 32, 1024 / 32), blk, 0, stream>>>(W_attn, WattnT, 1024, 3072);
  k_transpose_bf16<<<dim3(1024 / 32, 1024 / 32), blk, 0, stream>>>(W_proj, WprojT, 1024, 1024);
  k_transpose_bf16<<<dim3(4096 / 32, 1024 / 32), blk, 0, stream>>>(W_fc, WfcT, 1024, 4096);
  k_transpose_bf16<<<dim3(1024 / 32, 4096 / 32), blk, 0, stream>>>(W_mlp, WmlpT, 4096, 1024);

  k_layernorm_bf16<<<M, blk, 0, stream>>>(x, ln1_g, ln1_b, x1);
  // QKV: BN=128, grid 24*32=768 (%8==0), EPI3 split epilogue
  k_gemm_bt<3, 128><<<dim3(768), blk, 0, stream>>>(
      x1, WattnT, b_attn, nullptr, qkb, VT, M, 3072, 1024, 24);
  k_attention<<<dim3(512), blk, 0, stream>>>(qkb, VT, attno);
  // proj: BN=64, grid 16*32=512, EPI1 residual(x1) -> f32 x2
  k_gemm_bt<1, 64><<<dim3(512), blk, 0, stream>>>(
      attno, WprojT, b_proj, x1, x2, nullptr, M, 1024, 1024, 16);
  k_layernorm_bf16<<<M, blk, 0, stream>>>(x2, ln2_g, ln2_b, x3);
  // FC: BN=128, grid 32*32=1024, EPI2 gelu
  k_gemm_bt<2, 128><<<dim3(1024), blk, 0, stream>>>(
      x3, WfcT, b_fc, nullptr, hbuf, nullptr, M, 4096, 1024, 32);
  // MLP-proj: BN=64, grid 16*32=512, EPI1 residual(x3) -> f32 d_out
  k_gemm_bt<1, 64><<<dim3(512), blk, 0, stream>>>(
      hbuf, WmlpT, b_mlp, x3, d_out, nullptr, M, 1024, 4096, 16);
}

// Round 13
// 244.639 us; speedup vs baseline: 1.1356x; 1.0326x over previous
//
#include <hip/hip_runtime.h>
#include <cstdint>

typedef __attribute__((ext_vector_type(8))) short bf16x8;
typedef __attribute__((ext_vector_type(4))) float f32x4;
typedef __attribute__((ext_vector_type(16))) float f32x16;
typedef __attribute__((ext_vector_type(4))) unsigned short u16x4;
typedef __attribute__((ext_vector_type(4))) unsigned int u32x4;
typedef unsigned short u16;

#define LOG2E 1.44269504088896340736f

__device__ __forceinline__ u16 f2bf(float f) {
  unsigned u = __builtin_bit_cast(unsigned, f);
  u += 0x7FFFu + ((u >> 16) & 1u);
  return (u16)(u >> 16);
}
__device__ __forceinline__ float bf2f(u16 h) {
  return __builtin_bit_cast(float, ((unsigned)h) << 16);
}

#define GLOAD_LDS16(g, l)                                                              \
  __builtin_amdgcn_global_load_lds((const __attribute__((address_space(1))) void*)(g), \
                                   (__attribute__((address_space(3))) void*)(l), 16, 0, 0)

// ------------- fused weight transpose: all 4 matrices in one launch -------------
// f32[K][N] -> bf16[N][K]; block-range switch picks the matrix.
__global__ __launch_bounds__(256) void k_transpose_all(
    const float* __restrict__ W0, u16* __restrict__ T0,   // W_attn 1024x3072
    const float* __restrict__ W1, u16* __restrict__ T1,   // W_proj 1024x1024
    const float* __restrict__ W2, u16* __restrict__ T2,   // W_fc   1024x4096
    const float* __restrict__ W3, u16* __restrict__ T3) { // W_mlp  4096x1024
  __shared__ float tile[32][33];
  int b = blockIdx.x;
  const float* W;
  u16* Wt;
  int K, N, nx;
  if (b < 3072)        { W = W0; Wt = T0; K = 1024; N = 3072; nx = 96; }
  else if (b < 4096)   { b -= 3072; W = W1; Wt = T1; K = 1024; N = 1024; nx = 32; }
  else if (b < 8192)   { b -= 4096; W = W2; Wt = T2; K = 1024; N = 4096; nx = 128; }
  else                 { b -= 8192; W = W3; Wt = T3; K = 4096; N = 1024; nx = 32; }
  const int n0 = (b % nx) * 32, k0 = (b / nx) * 32;
  const int tid = threadIdx.x;
  const int tx = tid & 31, ty = tid >> 5;
#pragma unroll
  for (int i = 0; i < 32; i += 8)
    tile[ty + i][tx] = W[(size_t)(k0 + ty + i) * N + n0 + tx];
  __syncthreads();
#pragma unroll
  for (int i = 0; i < 32; i += 8)
    Wt[(size_t)(n0 + ty + i) * K + k0 + tx] = f2bf(tile[tx][ty + i]);
}

// ---------------- LayerNorm [row][1024] -> bf16 (f32 or bf16 input) ----------------
template <bool INF32>
__global__ __launch_bounds__(256) void k_layernorm(
    const void* __restrict__ xin, const float* __restrict__ g,
    const float* __restrict__ b, u16* __restrict__ y) {
  const int row = blockIdx.x, tid = threadIdx.x;
  float v0, v1, v2, v3;
  if (INF32) {
    const float4 v = ((const float4*)((const float*)xin + (size_t)row * 1024))[tid];
    v0 = v.x; v1 = v.y; v2 = v.z; v3 = v.w;
  } else {
    const u16x4 v = ((const u16x4*)((const u16*)xin + (size_t)row * 1024))[tid];
    v0 = bf2f(v[0]); v1 = bf2f(v[1]); v2 = bf2f(v[2]); v3 = bf2f(v[3]);
  }
  float s = v0 + v1 + v2 + v3;
#pragma unroll
  for (int m = 1; m < 64; m <<= 1) s += __shfl_xor(s, m);
  __shared__ float ps[8];
  if ((tid & 63) == 0) ps[tid >> 6] = s;
  __syncthreads();
  const float mean = (ps[0] + ps[1] + ps[2] + ps[3]) * (1.0f / 1024.0f);
  const float d0 = v0 - mean, d1 = v1 - mean, d2 = v2 - mean, d3 = v3 - mean;
  float s2 = d0 * d0 + d1 * d1 + d2 * d2 + d3 * d3;
#pragma unroll
  for (int m = 1; m < 64; m <<= 1) s2 += __shfl_xor(s2, m);
  if ((tid & 63) == 0) ps[4 + (tid >> 6)] = s2;
  __syncthreads();
  const float var = (ps[4] + ps[5] + ps[6] + ps[7]) * (1.0f / 1024.0f);
  const float rstd = rsqrtf(var + 1e-5f);
  const float4 gv = ((const float4*)g)[tid];
  const float4 bv = ((const float4*)b)[tid];
  u16x4 o;
  o[0] = f2bf(d0 * rstd * gv.x + bv.x);
  o[1] = f2bf(d1 * rstd * gv.y + bv.y);
  o[2] = f2bf(d2 * rstd * gv.z + bv.z);
  o[3] = f2bf(d3 * rstd * gv.w + bv.w);
  *(u16x4*)(y + (size_t)row * 1024 + tid * 4) = o;
}

__device__ __forceinline__ float gelu_f(float x) {
  const float u = 0.7978845608028654f * (x + 0.044715f * x * x * x);
  const float e = exp2f(u * 2.8853900817779268f);  // e^{2u}
  const float t = 1.0f - 2.0f / (e + 1.0f);        // tanh(u)
  return 0.5f * x * (1.0f + t);
}

// ---------------- 128xBN GEMM, single-buffered m97 structure ----------------
// BN=128: 2x2 waves; BN=64: 4x1 waves. 1-D grid + bijective XCD swizzle.
// EPI 0: bf16  EPI 1: f32 + bf16 residual  EPI 2: bf16+gelu  EPI 3: qkv split
// EPI 4: bf16 + bf16 residual
template <int EPI, int BN>
__global__ __launch_bounds__(256, 4) void k_gemm_bt(
    const u16* __restrict__ A, const u16* __restrict__ Bt,
    const float* __restrict__ bias, const u16* __restrict__ resid,
    void* __restrict__ out, u16* __restrict__ vt, int M, int N, int K, int nbx) {
  constexpr int BM = 128;
  __shared__ u16 As[BM * 64];
  __shared__ u16 Bs[BN * 64];
  const int tid = threadIdx.x;
  const int wg = ((blockIdx.x & 7) * (gridDim.x >> 3)) + (blockIdx.x >> 3);
  const int bx = wg % nbx, by = wg / nbx;
  const int rowBase = by * BM, colBase = bx * BN;
  const int w = tid >> 6, l = tid & 63;
  const int wm = (BN == 128) ? (w >> 1) : w;
  const int wn = (BN == 128) ? (w & 1) : 0;
  constexpr int MR = (BN == 128) ? 4 : 2;
  constexpr int WROWS = (BN == 128) ? 64 : 32;
  const int lrow = l & 15, lg = l >> 4;
  const int srow = tid >> 3, sslot = tid & 7;

  const f32x4 fz = {0.f, 0.f, 0.f, 0.f};
  f32x4 acc[MR][4];
#pragma unroll
  for (int m = 0; m < MR; m++)
#pragma unroll
    for (int n = 0; n < 4; n++) acc[m][n] = fz;

  const int NT = K >> 6;
  for (int kt = 0; kt < NT; ++kt) {
#pragma unroll
    for (int i = 0; i < BM / 32; i++) {
      const int r = srow + 32 * i;
      const int gs = sslot ^ (r & 7);
      GLOAD_LDS16(A + (size_t)(rowBase + r) * K + kt * 64 + gs * 8,
                  (char*)As + i * 4096 + tid * 16);
    }
#pragma unroll
    for (int i = 0; i < BN / 32; i++) {
      const int r = srow + 32 * i;
      const int gs = sslot ^ (r & 7);
      GLOAD_LDS16(Bt + (size_t)(colBase + r) * K + kt * 64 + gs * 8,
                  (char*)Bs + i * 4096 + tid * 16);
    }
    __syncthreads();
#pragma unroll
    for (int kc = 0; kc < 2; kc++) {
      bf16x8 av[MR], bv[4];
#pragma unroll
      for (int m = 0; m < MR; m++) {
        const int r = wm * WROWS + m * 16 + lrow;
        const int sl = (kc * 4 + lg) ^ (r & 7);
        av[m] = *(const bf16x8*)((const char*)As + r * 128 + sl * 16);
      }
#pragma unroll
      for (int n = 0; n < 4; n++) {
        const int r = wn * 64 + n * 16 + lrow;
        const int sl = (kc * 4 + lg) ^ (r & 7);
        bv[n] = *(const bf16x8*)((const char*)Bs + r * 128 + sl * 16);
      }
#pragma unroll
      for (int m = 0; m < MR; m++)
#pragma unroll
        for (int n = 0; n < 4; n++)
          acc[m][n] = __builtin_amdgcn_mfma_f32_16x16x32_bf16(av[m], bv[n], acc[m][n], 0, 0, 0);
    }
    __syncthreads();
  }
#pragma unroll
  for (int n = 0; n < 4; n++) {
    const int col = colBase + wn * 64 + n * 16 + lrow;
    const float bval = bias[col];
#pragma unroll
    for (int m = 0; m < MR; m++) {
      const int row0 = rowBase + wm * WROWS + m * 16 + lg * 4;
      if (EPI == 3 && col >= 2048) {
        const int c2 = col - 2048;
        const int hh = c2 >> 6, dd = c2 & 63;
        const int bat = row0 >> 11, tok0 = row0 & 2047;
        u16x4 pk;
#pragma unroll
        for (int r = 0; r < 4; r++) pk[r] = f2bf(acc[m][n][r] + bval);
        *(u16x4*)(vt + ((size_t)(bat * 16 + hh) * 64 + dd) * 2048 + tok0) = pk;
      } else if (EPI == 3) {
#pragma unroll
        for (int r = 0; r < 4; r++)
          ((u16*)out)[(size_t)(row0 + r) * 2048 + col] = f2bf(acc[m][n][r] + bval);
      } else {
#pragma unroll
        for (int r = 0; r < 4; r++) {
          const size_t idx = (size_t)(row0 + r) * N + col;
          float v = acc[m][n][r] + bval;
          if (EPI == 0) {
            ((u16*)out)[idx] = f2bf(v);
          } else if (EPI == 2) {
            ((u16*)out)[idx] = f2bf(gelu_f(v));
          } else if (EPI == 4) {
            ((u16*)out)[idx] = f2bf(v + bf2f(resid[idx]));
          } else {
            v += bf2f(resid[idx]);
            ((float*)out)[idx] = v;
          }
        }
      }
    }
  }
}

// ---------------- causal flash attention v5 (unchanged from R11/R12) ----------
__global__ __launch_bounds__(256, 2) void k_attention(
    const u16* __restrict__ qk, const u16* __restrict__ VT, u16* __restrict__ out) {
  const int S = 2048, E2 = 2048;
  const int bid = blockIdx.x;
  const int qt = 15 - (bid >> 5);
  const int bh = bid & 31;
  const int bat = bh >> 4, h = bh & 15;
  const u16* base = qk + (size_t)bat * S * E2;
  const u16* kbase = base + 1024 + h * 64;
  const u16* vbase = VT + (size_t)bh * 64 * S;
  const int tid = threadIdx.x, w = tid >> 6, l = tid & 63;
  const int l31 = l & 31, lh = l >> 5;
  __shared__ u16 Ks[2][64 * 64];
  __shared__ u16 Vs[2][64 * 64];
  const int srow = tid >> 3;
  const int gs = (tid & 7) ^ (srow & 7);
  const float sc = 0.125f * LOG2E;
  const float RTHR = 8.0f / sc;

  auto STAGE = [&](int bufi, int kb) {
#pragma unroll
    for (int round = 0; round < 2; round++) {
      const int r = srow + 32 * round;
      GLOAD_LDS16(kbase + (size_t)(kb + r) * E2 + gs * 8, (char*)Ks[bufi] + round * 4096 + tid * 16);
      GLOAD_LDS16(vbase + (size_t)r * S + kb + gs * 8, (char*)Vs[bufi] + round * 4096 + tid * 16);
    }
  };

  const int wq0 = qt * 128 + w * 32;
  const int qg = wq0 + l31;
  const int tdiag = wq0 >> 6;
  const int nkt = 2 * qt + 2;

  bf16x8 qf[4];
#pragma unroll
  for (int s = 0; s < 4; s++)
    qf[s] = *(const bf16x8*)(base + (size_t)qg * E2 + h * 64 + s * 16 + lh * 8);

  f32x16 o0, o1;
#pragma unroll
  for (int r = 0; r < 16; r++) { o0[r] = 0.f; o1[r] = 0.f; }
  float mrow = -1e30f, lsum = 0.f;

  STAGE(0, 0);
  __syncthreads();

  for (int t = 0; t < nkt; t++) {
    const int cur = t & 1;
    const int kb = t * 64;
    if (t + 1 < nkt) STAGE(cur ^ 1, kb + 64);
    if (t <= tdiag) {
      const u16* Kc = Ks[cur];
      const u16* Vc = Vs[cur];

      f32x16 sv0, sv1;
#pragma unroll
      for (int r = 0; r < 16; r++) { sv0[r] = 0.f; sv1[r] = 0.f; }
#pragma unroll
      for (int s = 0; s < 4; s++) {
        const int row0 = l31, row1 = 32 + l31;
        const int sl = s * 2 + lh;
        const bf16x8 k0 = *(const bf16x8*)(Kc + row0 * 64 + ((sl ^ (row0 & 7)) * 8));
        const bf16x8 k1 = *(const bf16x8*)(Kc + row1 * 64 + ((sl ^ (row1 & 7)) * 8));
        sv0 = __builtin_amdgcn_mfma_f32_32x32x16_bf16(k0, qf[s], sv0, 0, 0, 0);
        sv1 = __builtin_amdgcn_mfma_f32_32x32x16_bf16(k1, qf[s], sv1, 0, 0, 0);
      }

      if (t == tdiag) {
#pragma unroll
        for (int reg = 0; reg < 16; reg++) {
          const int kl = (reg & 3) + 8 * (reg >> 2) + 4 * lh;
          if (kb + kl > qg) sv0[reg] = -1e30f;
          if (kb + 32 + kl > qg) sv1[reg] = -1e30f;
        }
      }

      float tmax = sv0[0];
#pragma unroll
      for (int reg = 1; reg < 16; reg++) tmax = fmaxf(tmax, sv0[reg]);
#pragma unroll
      for (int reg = 0; reg < 16; reg++) tmax = fmaxf(tmax, sv1[reg]);
      tmax = fmaxf(tmax, __shfl_xor(tmax, 32));

      if (!__all(tmax - mrow <= RTHR)) {
        const float mnew = fmaxf(mrow, tmax);
        const float corr = exp2f((mrow - mnew) * sc);
        lsum *= corr;
#pragma unroll
        for (int reg = 0; reg < 16; reg++) { o0[reg] *= corr; o1[reg] *= corr; }
        mrow = mnew;
      }
      const float msc = mrow * sc;

      float p0[16], p1[16];
      float rsum = 0.f;
#pragma unroll
      for (int reg = 0; reg < 16; reg++) {
        p0[reg] = exp2f(fmaf(sv0[reg], sc, -msc));
        p1[reg] = exp2f(fmaf(sv1[reg], sc, -msc));
        rsum += p0[reg] + p1[reg];
      }
      rsum += __shfl_xor(rsum, 32);
      lsum += rsum;

      unsigned pk0[8], pk1[8], ex0[8], ex1[8];
#pragma unroll
      for (int j = 0; j < 8; j++) {
        asm("v_cvt_pk_bf16_f32 %0, %1, %2" : "=v"(pk0[j]) : "v"(p0[2 * j]), "v"(p0[2 * j + 1]));
        asm("v_cvt_pk_bf16_f32 %0, %1, %2" : "=v"(pk1[j]) : "v"(p1[2 * j]), "v"(p1[2 * j + 1]));
        ex0[j] = (unsigned)__shfl_xor((int)pk0[j], 32);
        ex1[j] = (unsigned)__shfl_xor((int)pk1[j], 32);
      }
      const bool lo = (lh == 0);

#pragma unroll
      for (int kh = 0; kh < 2; kh++) {
#pragma unroll
        for (int sl2 = 0; sl2 < 2; sl2++) {
          const int ks = kh * 2 + sl2;
          const unsigned* pk = kh ? pk1 : pk0;
          const unsigned* ex = kh ? ex1 : ex0;
          const int j0 = sl2 * 4;
          const unsigned b0 = lo ? pk[j0 + 0] : ex[j0 + 2];
          const unsigned b1 = lo ? pk[j0 + 1] : ex[j0 + 3];
          const unsigned b2 = lo ? ex[j0 + 0] : pk[j0 + 2];
          const unsigned b3 = lo ? ex[j0 + 1] : pk[j0 + 3];
          const u32x4 pbu = {b0, b1, b2, b3};
          const bf16x8 pb = __builtin_bit_cast(bf16x8, pbu);
          const int sl = ks * 2 + lh;
          const int r0 = l31, r1 = 32 + l31;
          const bf16x8 v0 = *(const bf16x8*)(Vc + r0 * 64 + ((sl ^ (r0 & 7)) * 8));
          const bf16x8 v1 = *(const bf16x8*)(Vc + r1 * 64 + ((sl ^ (r1 & 7)) * 8));
          o0 = __builtin_amdgcn_mfma_f32_32x32x16_bf16(v0, pb, o0, 0, 0, 0);
          o1 = __builtin_amdgcn_mfma_f32_32x32x16_bf16(v1, pb, o1, 0, 0, 0);
        }
      }
    }
    __syncthreads();
  }

  const float inv = 1.0f / lsum;
  const size_t orow = (size_t)(bat * S + qg) * 1024 + h * 64;
#pragma unroll
  for (int g = 0; g < 4; g++) {
    u16x4 s0, s1;
#pragma unroll
    for (int r = 0; r < 4; r++) {
      s0[r] = f2bf(o0[4 * g + r] * inv);
      s1[r] = f2bf(o1[4 * g + r] * inv);
    }
    const int d0 = 8 * g + 4 * lh;
    *(u16x4*)(out + orow + d0) = s0;
    *(u16x4*)(out + orow + 32 + d0) = s1;
  }
}

// ---------------- host launch ----------------
extern "C" void kernel_launch(void* const* d_in, const int* in_sizes, int n_in,
                              void* d_out, int out_size, void* d_ws, size_t ws_size,
                              hipStream_t stream) {
  (void)in_sizes; (void)n_in; (void)out_size; (void)ws_size;
  const float* x      = (const float*)d_in[0];
  const float* ln1_g  = (const float*)d_in[1];
  const float* ln1_b  = (const float*)d_in[2];
  const float* W_attn = (const float*)d_in[3];
  const float* b_attn = (const float*)d_in[4];
  const float* W_proj = (const float*)d_in[5];
  const float* b_proj = (const float*)d_in[6];
  const float* ln2_g  = (const float*)d_in[7];
  const float* ln2_b  = (const float*)d_in[8];
  const float* W_fc   = (const float*)d_in[9];
  const float* b_fc   = (const float*)d_in[10];
  const float* W_mlp  = (const float*)d_in[11];
  const float* b_mlp  = (const float*)d_in[12];

  const int M = 4096;  // B*S = 2*2048
  char* ws = (char*)d_ws;
  size_t off = 0;
  auto alloc = [&](size_t bytes) {
    void* p = ws + off;
    off += (bytes + 255) & ~(size_t)255;
    return p;
  };
  u16* WattnT = (u16*)alloc((size_t)3072 * 1024 * 2);
  u16* WprojT = (u16*)alloc((size_t)1024 * 1024 * 2);
  u16* WfcT   = (u16*)alloc((size_t)4096 * 1024 * 2);
  u16* WmlpT  = (u16*)alloc((size_t)1024 * 4096 * 2);
  u16* x1     = (u16*)alloc((size_t)M * 1024 * 2);
  u16* qkb    = (u16*)alloc((size_t)M * 2048 * 2);        // Q|K only
  u16* VT     = (u16*)alloc((size_t)32 * 64 * 2048 * 2);  // [b*h][d][tok]
  u16* attno  = (u16*)alloc((size_t)M * 1024 * 2);
  u16* x2     = (u16*)alloc((size_t)M * 1024 * 2);        // bf16 residual (was f32)
  u16* x3     = (u16*)alloc((size_t)M * 1024 * 2);
  u16* hbuf   = (u16*)alloc((size_t)M * 4096 * 2);

  const dim3 blk(256);
  // all 4 weight transposes in one launch (12288 tile-blocks)
  k_transpose_all<<<dim3(12288), blk, 0, stream>>>(
      W_attn, WattnT, W_proj, WprojT, W_fc, WfcT, W_mlp, WmlpT);

  k_layernorm<true><<<M, blk, 0, stream>>>(x, ln1_g, ln1_b, x1);
  // QKV: BN=128, grid 24*32=768, EPI3 split epilogue
  k_gemm_bt<3, 128><<<dim3(768), blk, 0, stream>>>(
      x1, WattnT, b_attn, nullptr, qkb, VT, M, 3072, 1024, 24);
  k_attention<<<dim3(512), blk, 0, stream>>>(qkb, VT, attno);
  // proj: BN=64, grid 512, EPI4 residual(x1) -> bf16 x2
  k_gemm_bt<4, 64><<<dim3(512), blk, 0, stream>>>(
      attno, WprojT, b_proj, x1, x2, nullptr, M, 1024, 1024, 16);
  k_layernorm<false><<<M, blk, 0, stream>>>(x2, ln2_g, ln2_b, x3);
  // FC: BN=128, grid 1024, EPI2 gelu
  k_gemm_bt<2, 128><<<dim3(1024), blk, 0, stream>>>(
      x3, WfcT, b_fc, nullptr, hbuf, nullptr, M, 4096, 1024, 32);
  // MLP-proj: BN=64, grid 512, EPI1 residual(x3) -> f32 d_out
  k_gemm_bt<1, 64><<<dim3(512), blk, 0, stream>>>(
      hbuf, WmlpT, b_mlp, x3, d_out, nullptr, M, 1024, 4096, 16);
}